// Round 1
// baseline (336.816 us; speedup 1.0000x reference)
//
#include <hip/hip_runtime.h>

// GovernanceAwareAttention on MI355X (gfx950).
// Key insight: governance bias is constant along the key axis -> softmax
// invariant -> context/entropy/concentration do NOT depend on it; only
// `influence` needs gov_scores. So: bf16 MFMA GEMM for Q/K/V/GK projections,
// flash attention with online softmax (carrying m, l, sum(p*s) per row for
// entropy and 1/l for concentration), small f32 side kernels for influence.
//
// B=2, S=2048, H=1024, NH=16, HD=64. d_out = context(4194304 f32) + 3 scalars.
// Workspace use: ~59 MB.

typedef unsigned short u16;
typedef __attribute__((ext_vector_type(8))) short bf16x8;   // 8 bf16 = 4 VGPR
typedef __attribute__((ext_vector_type(4))) float f32x4;
typedef __attribute__((ext_vector_type(4))) u16 u16x4;
typedef __attribute__((ext_vector_type(4))) float float4v;

typedef const __attribute__((address_space(1))) void gvoid_t;
typedef __attribute__((address_space(3))) void lvoid_t;

__device__ __forceinline__ void gl_lds16(const void* g, void* l) {
  // async global->LDS, 16B/lane; LDS dest must be wave-uniform base (HW adds lane*16)
  __builtin_amdgcn_global_load_lds((gvoid_t*)g, (lvoid_t*)l, 16, 0, 0);
}

__device__ __forceinline__ u16 f2bf(float x) {  // RNE f32->bf16
  union { float f; unsigned u; } v; v.f = x;
  unsigned r = v.u + 0x7fffu + ((v.u >> 16) & 1u);
  return (u16)(r >> 16);
}
__device__ __forceinline__ float bf2f(u16 h) {
  union { unsigned u; float f; } v; v.u = ((unsigned)h) << 16; return v.f;
}

// ---------------- conversion kernels ----------------

// hs f32 [4096x1024] -> bf16, 8 elems/thread. grid 2048 x 256.
__global__ void conv_hs(const float* __restrict__ in, u16* __restrict__ out) {
  int i = blockIdx.x * 256 + threadIdx.x;
  const float4v* in4 = (const float4v*)in;
  float4v a = in4[i * 2], b = in4[i * 2 + 1];
  bf16x8 v;
  v[0] = (short)f2bf(a.x); v[1] = (short)f2bf(a.y);
  v[2] = (short)f2bf(a.z); v[3] = (short)f2bf(a.w);
  v[4] = (short)f2bf(b.x); v[5] = (short)f2bf(b.y);
  v[6] = (short)f2bf(b.z); v[7] = (short)f2bf(b.w);
  *(bf16x8*)&out[(size_t)i * 8] = v;
}

// W [1024k x 1024n] f32 -> WB[(mat*1024+n)][k] bf16 (transposed). grid (256,4) x 256.
__global__ void conv_w(const float* __restrict__ W0, const float* __restrict__ W1,
                       const float* __restrict__ W2, const float* __restrict__ W3,
                       u16* __restrict__ WB) {
  __shared__ __align__(16) u16 T[64][72];  // pad to 144B rows (16B multiple)
  int mat = blockIdx.y;
  const float* W = (mat == 0) ? W0 : (mat == 1) ? W1 : (mat == 2) ? W2 : W3;
  int k0 = (blockIdx.x >> 4) * 64, n0 = (blockIdx.x & 15) * 64;
  int tx = threadIdx.x;
#pragma unroll
  for (int p = 0; p < 4; ++p) {
    int chunk = p * 256 + tx;           // 1024 float4 chunks
    int row = chunk >> 4, cp = chunk & 15;
    float4v v = *(const float4v*)&W[(size_t)(k0 + row) * 1024 + n0 + cp * 4];
    u16x4 o; o.x = f2bf(v.x); o.y = f2bf(v.y); o.z = f2bf(v.z); o.w = f2bf(v.w);
    *(u16x4*)&T[row][cp * 4] = o;
  }
  __syncthreads();
#pragma unroll
  for (int p = 0; p < 2; ++p) {
    int chunk = p * 256 + tx;           // 512 out chunks of 8 bf16
    int nrow = chunk >> 3, cp = chunk & 7;
    bf16x8 v;
#pragma unroll
    for (int e = 0; e < 8; ++e) v[e] = (short)T[cp * 8 + e][nrow];
    *(bf16x8*)&WB[(size_t)(mat * 1024 + n0 + nrow) * 1024 + k0 + cp * 8] = v;
  }
}

// ---------------- projection GEMM (m97 structure) ----------------
// C[4096 x 4096] = A[4096x1024]bf16 * WB^T, +bias, Q pre-scaled by 1/8,
// outputs split to Qb,Kb,Vb,GKb bf16 [4096][1024]. grid 1024 x 256.
__global__ __launch_bounds__(256, 2) void gemm_qkvg(
    const u16* __restrict__ A, const u16* __restrict__ Bw,
    const float* __restrict__ bq, const float* __restrict__ bk,
    const float* __restrict__ bv, const float* __restrict__ bgk,
    u16* __restrict__ Qb, u16* __restrict__ Kb,
    u16* __restrict__ Vb, u16* __restrict__ GKb) {
  __shared__ __align__(16) u16 As[128 * 32];
  __shared__ __align__(16) u16 Bs[128 * 32];
  const int tid = threadIdx.x, lane = tid & 63, wv = tid >> 6;
  const int li = lane & 15, quad = lane >> 4;
  const int bid = blockIdx.x;
  const int nb = bid & 31, mb = bid >> 5;
  const u16* Ap = A + (size_t)(mb * 128) * 1024;
  const u16* Bp = Bw + (size_t)(nb * 128) * 1024;
  const int wm0 = (wv >> 1) * 64, wn0 = (wv & 1) * 64;

  f32x4 acc[4][4];
#pragma unroll
  for (int t = 0; t < 4; ++t)
#pragma unroll
    for (int u = 0; u < 4; ++u) acc[t][u] = (f32x4){0.f, 0.f, 0.f, 0.f};

  for (int kt = 0; kt < 32; ++kt) {
    __syncthreads();
#pragma unroll
    for (int jj = 0; jj < 2; ++jj) {      // 8 x 1KB issues each for A and B
      int j = wv * 2 + jj;
      int row = j * 16 + (lane >> 2);
      int co = lane & 3;
      gl_lds16(Ap + (size_t)row * 1024 + kt * 32 + co * 8, &As[j * 512]);
      gl_lds16(Bp + (size_t)row * 1024 + kt * 32 + co * 8, &Bs[j * 512]);
    }
    __syncthreads();
    bf16x8 af[4], bf[4];
#pragma unroll
    for (int t = 0; t < 4; ++t)
      af[t] = *(const bf16x8*)&As[(wm0 + t * 16 + li) * 32 + quad * 8];
#pragma unroll
    for (int u = 0; u < 4; ++u)
      bf[u] = *(const bf16x8*)&Bs[(wn0 + u * 16 + li) * 32 + quad * 8];
#pragma unroll
    for (int t = 0; t < 4; ++t)
#pragma unroll
      for (int u = 0; u < 4; ++u)
        acc[t][u] = __builtin_amdgcn_mfma_f32_16x16x32_bf16(af[t], bf[u], acc[t][u], 0, 0, 0);
  }

  const int nbase = nb * 128;
  const int mat = nbase >> 10;            // which weight matrix (block never straddles)
  const float* bias = (mat == 0) ? bq : (mat == 1) ? bk : (mat == 2) ? bv : bgk;
  u16* outp = (mat == 0) ? Qb : (mat == 1) ? Kb : (mat == 2) ? Vb : GKb;
  const float qscale = (mat == 0) ? 0.125f : 1.0f;  // fold 1/sqrt(64) into Q
#pragma unroll
  for (int t = 0; t < 4; ++t)
#pragma unroll
    for (int u = 0; u < 4; ++u) {
      int col = (nbase & 1023) + wn0 + u * 16 + li;
      float bb = bias[col];
#pragma unroll
      for (int r = 0; r < 4; ++r) {
        int row = mb * 128 + wm0 + t * 16 + quad * 4 + r;
        outp[(size_t)row * 1024 + col] = f2bf((acc[t][u][r] + bb) * qscale);
      }
    }
}

// ---------------- V transpose: Vb[b][s][d] -> Vt[b][d][s] ----------------
__global__ void transpose_v(const u16* __restrict__ Vb, u16* __restrict__ Vt) {
  __shared__ __align__(16) u16 T[64][72];
  int s0 = blockIdx.x * 64, d0 = blockIdx.y * 64, b = blockIdx.z;
  const u16* inp = Vb + (size_t)b * 2048 * 1024;
  u16* outp = Vt + (size_t)b * 1024 * 2048;
  int tx = threadIdx.x;
#pragma unroll
  for (int p = 0; p < 2; ++p) {
    int chunk = p * 256 + tx;
    int row = chunk >> 3, cp = chunk & 7;
    *(bf16x8*)&T[row][cp * 8] =
        *(const bf16x8*)&inp[(size_t)(s0 + row) * 1024 + d0 + cp * 8];
  }
  __syncthreads();
#pragma unroll
  for (int p = 0; p < 2; ++p) {
    int chunk = p * 256 + tx;
    int drow = chunk >> 3, cp = chunk & 7;
    bf16x8 v;
#pragma unroll
    for (int e = 0; e < 8; ++e) v[e] = (short)T[cp * 8 + e][drow];
    *(bf16x8*)&outp[(size_t)(d0 + drow) * 2048 + s0 + cp * 8] = v;
  }
}

// ---------------- gq = ge @ Wgq + bgq (f32, tiny) ----------------
__global__ void gq_kernel(const float* __restrict__ ge, const float* __restrict__ Wgq,
                          const float* __restrict__ bgq, float* __restrict__ gq) {
  int t = blockIdx.x * 256 + threadIdx.x;     // 2048 threads
  int b = t >> 10, col = t & 1023;
  float s = bgq[col];
  for (int k = 0; k < 1024; ++k) s += ge[b * 1024 + k] * Wgq[(size_t)k * 1024 + col];
  gq[t] = s;
}

// ---------------- flash attention ----------------
// grid 512 x 256. bh = bx&31 (XCD-L2 locality), qb = bx>>5.
__global__ __launch_bounds__(256, 2) void attn_kernel(
    const u16* __restrict__ Qb, const u16* __restrict__ Kb,
    const u16* __restrict__ Vt, float* __restrict__ out,
    float* __restrict__ acc /*[0]=ent,[1]=conc*/) {
  __shared__ __align__(16) u16 Qs[128 * 64];   // XOR-swizzled 16B chunks
  __shared__ __align__(16) u16 Ks[128 * 64];
  __shared__ __align__(16) u16 Vs[64 * 128];
  __shared__ __align__(16) u16 Ps[4][32 * 40]; // per-wave P, 80B rows (pad)
  __shared__ float redE[4], redC[4];

  const int tid = threadIdx.x, lane = tid & 63, wv = tid >> 6;
  const int li = lane & 15, quad = lane >> 4;
  const int bx = blockIdx.x;
  const int bh = bx & 31, qb = bx >> 5;
  const int b = bh >> 4, h = bh & 15;

  const u16* Qp = Qb + (size_t)(b * 2048 + qb * 128) * 1024 + h * 64;
  const u16* Kp = Kb + (size_t)(b * 2048) * 1024 + h * 64;
  const u16* Vp = Vt + (size_t)b * (1024 * 2048) + (size_t)(h * 64) * 2048;

  // stage Q once (swizzle: row r, chunk pos p holds data chunk p^(r&7))
#pragma unroll
  for (int jj = 0; jj < 4; ++jj) {
    int j = wv * 4 + jj;
    int row = j * 8 + (lane >> 3);
    int c16 = (lane & 7) ^ (row & 7);
    gl_lds16(Qp + (size_t)row * 1024 + c16 * 8, &Qs[j * 512]);
  }

  float m_st[2][4], l_st[2][4], e_st[2][4];
  f32x4 accO[2][4];
#pragma unroll
  for (int t = 0; t < 2; ++t)
#pragma unroll
    for (int r = 0; r < 4; ++r) { m_st[t][r] = -3.0e38f; l_st[t][r] = 0.f; e_st[t][r] = 0.f; }
#pragma unroll
  for (int t = 0; t < 2; ++t)
#pragma unroll
    for (int d = 0; d < 4; ++d) accO[t][d] = (f32x4){0.f, 0.f, 0.f, 0.f};

  const int wq0 = wv * 32;

  for (int kt = 0; kt < 16; ++kt) {
    __syncthreads();
    const u16* Kpt = Kp + (size_t)kt * 128 * 1024;
#pragma unroll
    for (int jj = 0; jj < 4; ++jj) {
      int j = wv * 4 + jj;
      int row = j * 8 + (lane >> 3);
      int c16 = (lane & 7) ^ (row & 7);
      gl_lds16(Kpt + (size_t)row * 1024 + c16 * 8, &Ks[j * 512]);
    }
#pragma unroll
    for (int jj = 0; jj < 4; ++jj) {
      int j = wv * 4 + jj;
      int row = j * 4 + (lane >> 4);
      int c16 = (lane & 15) ^ (row & 7);
      gl_lds16(Vp + (size_t)row * 2048 + kt * 128 + c16 * 8, &Vs[j * 512]);
    }
    __syncthreads();

    // S = Q K^T (Q pre-scaled)
    bf16x8 af[2][2];
#pragma unroll
    for (int t = 0; t < 2; ++t)
#pragma unroll
      for (int ks = 0; ks < 2; ++ks) {
        int row = wq0 + t * 16 + li;
        int p = (ks * 4 + quad) ^ (row & 7);
        af[t][ks] = *(const bf16x8*)&Qs[row * 64 + p * 8];
      }
    f32x4 S[2][8];
#pragma unroll
    for (int u = 0; u < 8; ++u) {
      int row = u * 16 + li;
      bf16x8 b0 = *(const bf16x8*)&Ks[row * 64 + ((quad) ^ (row & 7)) * 8];
      bf16x8 b1 = *(const bf16x8*)&Ks[row * 64 + ((4 + quad) ^ (row & 7)) * 8];
#pragma unroll
      for (int t = 0; t < 2; ++t) {
        f32x4 c = {0.f, 0.f, 0.f, 0.f};
        c = __builtin_amdgcn_mfma_f32_16x16x32_bf16(af[t][0], b0, c, 0, 0, 0);
        c = __builtin_amdgcn_mfma_f32_16x16x32_bf16(af[t][1], b1, c, 0, 0, 0);
        S[t][u] = c;
      }
    }

    // online softmax; rows = (t, quad, r); 16 cols per u-tile across lanes
    float alpha_[2][4];
#pragma unroll
    for (int t = 0; t < 2; ++t)
#pragma unroll
      for (int r = 0; r < 4; ++r) {
        float cm = S[t][0][r];
#pragma unroll
        for (int u = 1; u < 8; ++u) cm = fmaxf(cm, S[t][u][r]);
        cm = fmaxf(cm, __shfl_xor(cm, 1, 64));
        cm = fmaxf(cm, __shfl_xor(cm, 2, 64));
        cm = fmaxf(cm, __shfl_xor(cm, 4, 64));
        cm = fmaxf(cm, __shfl_xor(cm, 8, 64));
        float mo = m_st[t][r];
        float mn = fmaxf(mo, cm);
        m_st[t][r] = mn;
        float al = __expf(mo - mn);
        alpha_[t][r] = al;
        float ps = 0.f, es = 0.f;
#pragma unroll
        for (int u = 0; u < 8; ++u) {
          float s = S[t][u][r];
          float p = __expf(s - mn);
          ps += p;
          es = __builtin_fmaf(p, s, es);
          S[t][u][r] = p;
        }
        ps += __shfl_xor(ps, 1, 64); es += __shfl_xor(es, 1, 64);
        ps += __shfl_xor(ps, 2, 64); es += __shfl_xor(es, 2, 64);
        ps += __shfl_xor(ps, 4, 64); es += __shfl_xor(es, 4, 64);
        ps += __shfl_xor(ps, 8, 64); es += __shfl_xor(es, 8, 64);
        l_st[t][r] = l_st[t][r] * al + ps;
        e_st[t][r] = e_st[t][r] * al + es;
      }
#pragma unroll
    for (int t = 0; t < 2; ++t)
#pragma unroll
      for (int d = 0; d < 4; ++d)
#pragma unroll
        for (int r = 0; r < 4; ++r) accO[t][d][r] *= alpha_[t][r];

    // PV: P C-layout -> A-layout via per-wave LDS chunk, 32 keys at a time
    u16* Pw = &Ps[wv][0];
#pragma unroll
    for (int ks2 = 0; ks2 < 4; ++ks2) {
#pragma unroll
      for (int t = 0; t < 2; ++t)
#pragma unroll
        for (int uu = 0; uu < 2; ++uu) {
          int u = ks2 * 2 + uu;
#pragma unroll
          for (int r = 0; r < 4; ++r) {
            int row = t * 16 + quad * 4 + r;
            Pw[row * 40 + uu * 16 + li] = f2bf(S[t][u][r]);
          }
        }
#pragma unroll
      for (int t = 0; t < 2; ++t) {
        bf16x8 ap = *(const bf16x8*)&Pw[(t * 16 + li) * 40 + quad * 8];
#pragma unroll
        for (int d = 0; d < 4; ++d) {
          int vrow = d * 16 + li;
          int p = (ks2 * 4 + quad) ^ (vrow & 7);
          bf16x8 bv = *(const bf16x8*)&Vs[vrow * 128 + p * 8];
          accO[t][d] = __builtin_amdgcn_mfma_f32_16x16x32_bf16(ap, bv, accO[t][d], 0, 0, 0);
        }
      }
    }
  }

  // epilogue: context write + per-row stats
  float* outp = out + (size_t)(b * 2048 + qb * 128 + wq0) * 1024 + h * 64;
  float entw = 0.f, concw = 0.f;
#pragma unroll
  for (int t = 0; t < 2; ++t)
#pragma unroll
    for (int r = 0; r < 4; ++r) {
      float l = l_st[t][r];
      float inv = 1.0f / l;
      entw += m_st[t][r] + __logf(l) - e_st[t][r] * inv;  // -sum p ln p
      concw += inv;                                       // max prob = 1/l
      int row = t * 16 + quad * 4 + r;
#pragma unroll
      for (int d = 0; d < 4; ++d)
        outp[(size_t)row * 1024 + d * 16 + li] = accO[t][d][r] * inv;
    }
#pragma unroll
  for (int off = 1; off < 64; off <<= 1) {
    entw += __shfl_xor(entw, off, 64);
    concw += __shfl_xor(concw, off, 64);
  }
  if (lane == 0) { redE[wv] = entw * (1.f / 16.f); redC[wv] = concw * (1.f / 16.f); }
  __syncthreads();
  if (tid == 0) {
    atomicAdd(&acc[0], redE[0] + redE[1] + redE[2] + redE[3]);
    atomicAdd(&acc[1], redC[0] + redC[1] + redC[2] + redC[3]);
  }
}

// ---------------- influence: sum |gq . gk| over (b,h,s) ----------------
__global__ void gov_kernel(const u16* __restrict__ GKb, const float* __restrict__ gq,
                           float* __restrict__ acc_inf) {
  __shared__ float redI[4];
  int lane = threadIdx.x & 63, wv = threadIdx.x >> 6;
  int wid = blockIdx.x * 4 + wv;          // one wave per (b,s)
  int b = wid >> 11, s = wid & 2047;
  const u16* gk = GKb + (size_t)(b * 2048 + s) * 1024 + lane * 16;
  const float* gqp = gq + b * 1024 + lane * 16;
  bf16x8 g0 = *(const bf16x8*)gk, g1 = *(const bf16x8*)(gk + 8);
  float4v q0 = *(const float4v*)&gqp[0], q1 = *(const float4v*)&gqp[4];
  float4v q2 = *(const float4v*)&gqp[8], q3 = *(const float4v*)&gqp[12];
  float sum = 0.f;
  sum += bf2f((u16)g0[0]) * q0.x + bf2f((u16)g0[1]) * q0.y +
         bf2f((u16)g0[2]) * q0.z + bf2f((u16)g0[3]) * q0.w;
  sum += bf2f((u16)g0[4]) * q1.x + bf2f((u16)g0[5]) * q1.y +
         bf2f((u16)g0[6]) * q1.z + bf2f((u16)g0[7]) * q1.w;
  sum += bf2f((u16)g1[0]) * q2.x + bf2f((u16)g1[1]) * q2.y +
         bf2f((u16)g1[2]) * q2.z + bf2f((u16)g1[3]) * q2.w;
  sum += bf2f((u16)g1[4]) * q3.x + bf2f((u16)g1[5]) * q3.y +
         bf2f((u16)g1[6]) * q3.z + bf2f((u16)g1[7]) * q3.w;
  // 4 lanes per head -> head sum
  sum += __shfl_xor(sum, 1, 64);
  sum += __shfl_xor(sum, 2, 64);
  float v = ((lane & 3) == 0) ? fabsf(sum) : 0.f;
  v += __shfl_xor(v, 4, 64);
  v += __shfl_xor(v, 8, 64);
  v += __shfl_xor(v, 16, 64);
  v += __shfl_xor(v, 32, 64);
  if (lane == 0) redI[wv] = v;
  __syncthreads();
  if (threadIdx.x == 0)
    atomicAdd(acc_inf, redI[0] + redI[1] + redI[2] + redI[3]);
}

__global__ void finalize(const float* __restrict__ acc, float* __restrict__ out) {
  if (threadIdx.x == 0) {
    out[0] = acc[0] * (1.f / 65536.f);  // entropy
    out[1] = acc[2] * (1.f / 65536.f);  // influence
    out[2] = acc[1] * (1.f / 65536.f);  // concentration
  }
}

extern "C" void kernel_launch(void* const* d_in, const int* in_sizes, int n_in,
                              void* d_out, int out_size, void* d_ws, size_t ws_size,
                              hipStream_t stream) {
  (void)in_sizes; (void)n_in; (void)out_size; (void)ws_size;
  const float* hs  = (const float*)d_in[0];
  const float* ge  = (const float*)d_in[1];
  const float* Wq  = (const float*)d_in[2];
  const float* bq  = (const float*)d_in[3];
  const float* Wk  = (const float*)d_in[4];
  const float* bk  = (const float*)d_in[5];
  const float* Wv  = (const float*)d_in[6];
  const float* bv  = (const float*)d_in[7];
  const float* Wgq = (const float*)d_in[8];
  const float* bgq = (const float*)d_in[9];
  const float* Wgk = (const float*)d_in[10];
  const float* bgk = (const float*)d_in[11];

  char* ws = (char*)d_ws;
  u16* hsB = (u16*)(ws);
  u16* WB  = (u16*)(ws + (size_t)(8 << 20));
  u16* Qb  = (u16*)(ws + (size_t)(16 << 20));
  u16* Kb  = (u16*)(ws + (size_t)(24 << 20));
  u16* Vb  = (u16*)(ws + (size_t)(32 << 20));
  u16* GKb = (u16*)(ws + (size_t)(40 << 20));
  u16* Vt  = (u16*)(ws + (size_t)(48 << 20));
  float* gq  = (float*)(ws + (size_t)(56 << 20));
  float* acc = (float*)(ws + (size_t)(56 << 20) + 16384);
  float* out = (float*)d_out;

  hipMemsetAsync(acc, 0, 3 * sizeof(float), stream);
  conv_hs<<<2048, 256, 0, stream>>>(hs, hsB);
  conv_w<<<dim3(256, 4), 256, 0, stream>>>(Wq, Wk, Wv, Wgk, WB);
  gemm_qkvg<<<1024, 256, 0, stream>>>(hsB, WB, bq, bk, bv, bgk, Qb, Kb, Vb, GKb);
  transpose_v<<<dim3(32, 16, 2), 256, 0, stream>>>(Vb, Vt);
  gq_kernel<<<8, 256, 0, stream>>>(ge, Wgq, bgq, gq);
  attn_kernel<<<512, 256, 0, stream>>>(Qb, Kb, Vt, out, acc);
  gov_kernel<<<1024, 256, 0, stream>>>(GKb, gq, acc + 2);
  finalize<<<1, 64, 0, stream>>>(acc, out + 4194304);
}

// Round 2
// 241.201 us; speedup vs baseline: 1.3964x; 1.3964x over previous
//
#include <hip/hip_runtime.h>

// GovernanceAwareAttention on MI355X (gfx950). Round 2.
// Governance bias is constant along key axis -> softmax invariant -> only
// `influence` needs gov_scores. bf16 MFMA for projections + flash attention.
//
// R2 change: attention computes S^T = K*Q^T (operand swap) so softmax is
// in-lane (shuffles 96->4 per wave-kt), P^T repack uses v_perm packed
// ds_write_b64 (64 b16 writes -> 16 b64), Q-frags live in registers (Qs LDS
// deleted), V A-frags reused across query tiles (32->16 reads). LDS-pipe ops
// per wave-kt ~124 -> ~60. gq_kernel parallelized via k-split + atomics.

typedef unsigned short u16;
typedef __attribute__((ext_vector_type(8))) short bf16x8;   // 8 bf16 = 4 VGPR
typedef __attribute__((ext_vector_type(4))) float f32x4;
typedef __attribute__((ext_vector_type(4))) u16 u16x4;
typedef __attribute__((ext_vector_type(4))) float float4v;

typedef const __attribute__((address_space(1))) void gvoid_t;
typedef __attribute__((address_space(3))) void lvoid_t;

__device__ __forceinline__ void gl_lds16(const void* g, void* l) {
  // async global->LDS, 16B/lane; LDS dest is wave-uniform base + lane*16
  __builtin_amdgcn_global_load_lds((gvoid_t*)g, (lvoid_t*)l, 16, 0, 0);
}

__device__ __forceinline__ u16 f2bf(float x) {  // RNE f32->bf16
  union { float f; unsigned u; } v; v.f = x;
  unsigned r = v.u + 0x7fffu + ((v.u >> 16) & 1u);
  return (u16)(r >> 16);
}
__device__ __forceinline__ float bf2f(u16 h) {
  union { unsigned u; float f; } v; v.u = ((unsigned)h) << 16; return v.f;
}
// pack two f32 -> two truncated bf16 in one v_perm_b32 (lo in low half)
__device__ __forceinline__ unsigned pk2(float hi, float lo) {
  union { float f; unsigned u; } a, b; a.f = hi; b.f = lo;
  return __builtin_amdgcn_perm(a.u, b.u, 0x07060302u);
}

// ---------------- conversion kernels ----------------

__global__ void conv_hs(const float* __restrict__ in, u16* __restrict__ out) {
  int i = blockIdx.x * 256 + threadIdx.x;
  const float4v* in4 = (const float4v*)in;
  float4v a = in4[i * 2], b = in4[i * 2 + 1];
  bf16x8 v;
  v[0] = (short)f2bf(a.x); v[1] = (short)f2bf(a.y);
  v[2] = (short)f2bf(a.z); v[3] = (short)f2bf(a.w);
  v[4] = (short)f2bf(b.x); v[5] = (short)f2bf(b.y);
  v[6] = (short)f2bf(b.z); v[7] = (short)f2bf(b.w);
  *(bf16x8*)&out[(size_t)i * 8] = v;
}

// W [1024k x 1024n] f32 -> WB[(mat*1024+n)][k] bf16 (transposed). grid (256,4) x 256.
__global__ void conv_w(const float* __restrict__ W0, const float* __restrict__ W1,
                       const float* __restrict__ W2, const float* __restrict__ W3,
                       u16* __restrict__ WB) {
  __shared__ __align__(16) u16 T[64][72];
  int mat = blockIdx.y;
  const float* W = (mat == 0) ? W0 : (mat == 1) ? W1 : (mat == 2) ? W2 : W3;
  int k0 = (blockIdx.x >> 4) * 64, n0 = (blockIdx.x & 15) * 64;
  int tx = threadIdx.x;
#pragma unroll
  for (int p = 0; p < 4; ++p) {
    int chunk = p * 256 + tx;
    int row = chunk >> 4, cp = chunk & 15;
    float4v v = *(const float4v*)&W[(size_t)(k0 + row) * 1024 + n0 + cp * 4];
    u16x4 o; o.x = f2bf(v.x); o.y = f2bf(v.y); o.z = f2bf(v.z); o.w = f2bf(v.w);
    *(u16x4*)&T[row][cp * 4] = o;
  }
  __syncthreads();
#pragma unroll
  for (int p = 0; p < 2; ++p) {
    int chunk = p * 256 + tx;
    int nrow = chunk >> 3, cp = chunk & 7;
    bf16x8 v;
#pragma unroll
    for (int e = 0; e < 8; ++e) v[e] = (short)T[cp * 8 + e][nrow];
    *(bf16x8*)&WB[(size_t)(mat * 1024 + n0 + nrow) * 1024 + k0 + cp * 8] = v;
  }
}

// ---------------- projection GEMM (m97 structure) ----------------
__global__ __launch_bounds__(256, 2) void gemm_qkvg(
    const u16* __restrict__ A, const u16* __restrict__ Bw,
    const float* __restrict__ bq, const float* __restrict__ bk,
    const float* __restrict__ bv, const float* __restrict__ bgk,
    u16* __restrict__ Qb, u16* __restrict__ Kb,
    u16* __restrict__ Vb, u16* __restrict__ GKb) {
  __shared__ __align__(16) u16 As[128 * 32];
  __shared__ __align__(16) u16 Bs[128 * 32];
  const int tid = threadIdx.x, lane = tid & 63, wv = tid >> 6;
  const int li = lane & 15, quad = lane >> 4;
  const int bid = blockIdx.x;
  const int nb = bid & 31, mb = bid >> 5;
  const u16* Ap = A + (size_t)(mb * 128) * 1024;
  const u16* Bp = Bw + (size_t)(nb * 128) * 1024;
  const int wm0 = (wv >> 1) * 64, wn0 = (wv & 1) * 64;

  f32x4 acc[4][4];
#pragma unroll
  for (int t = 0; t < 4; ++t)
#pragma unroll
    for (int u = 0; u < 4; ++u) acc[t][u] = (f32x4){0.f, 0.f, 0.f, 0.f};

  for (int kt = 0; kt < 32; ++kt) {
    __syncthreads();
#pragma unroll
    for (int jj = 0; jj < 2; ++jj) {
      int j = wv * 2 + jj;
      int row = j * 16 + (lane >> 2);
      int co = lane & 3;
      gl_lds16(Ap + (size_t)row * 1024 + kt * 32 + co * 8, &As[j * 512]);
      gl_lds16(Bp + (size_t)row * 1024 + kt * 32 + co * 8, &Bs[j * 512]);
    }
    __syncthreads();
    bf16x8 af[4], bf[4];
#pragma unroll
    for (int t = 0; t < 4; ++t)
      af[t] = *(const bf16x8*)&As[(wm0 + t * 16 + li) * 32 + quad * 8];
#pragma unroll
    for (int u = 0; u < 4; ++u)
      bf[u] = *(const bf16x8*)&Bs[(wn0 + u * 16 + li) * 32 + quad * 8];
#pragma unroll
    for (int t = 0; t < 4; ++t)
#pragma unroll
      for (int u = 0; u < 4; ++u)
        acc[t][u] = __builtin_amdgcn_mfma_f32_16x16x32_bf16(af[t], bf[u], acc[t][u], 0, 0, 0);
  }

  const int nbase = nb * 128;
  const int mat = nbase >> 10;
  const float* bias = (mat == 0) ? bq : (mat == 1) ? bk : (mat == 2) ? bv : bgk;
  u16* outp = (mat == 0) ? Qb : (mat == 1) ? Kb : (mat == 2) ? Vb : GKb;
  const float qscale = (mat == 0) ? 0.125f : 1.0f;  // fold 1/sqrt(64) into Q
#pragma unroll
  for (int t = 0; t < 4; ++t)
#pragma unroll
    for (int u = 0; u < 4; ++u) {
      int col = (nbase & 1023) + wn0 + u * 16 + li;
      float bb = bias[col];
#pragma unroll
      for (int r = 0; r < 4; ++r) {
        int row = mb * 128 + wm0 + t * 16 + quad * 4 + r;
        outp[(size_t)row * 1024 + col] = f2bf((acc[t][u][r] + bb) * qscale);
      }
    }
}

// ---------------- V transpose: Vb[b][s][d] -> Vt[b][d][s] ----------------
__global__ void transpose_v(const u16* __restrict__ Vb, u16* __restrict__ Vt) {
  __shared__ __align__(16) u16 T[64][72];
  int s0 = blockIdx.x * 64, d0 = blockIdx.y * 64, b = blockIdx.z;
  const u16* inp = Vb + (size_t)b * 2048 * 1024;
  u16* outp = Vt + (size_t)b * 1024 * 2048;
  int tx = threadIdx.x;
#pragma unroll
  for (int p = 0; p < 2; ++p) {
    int chunk = p * 256 + tx;
    int row = chunk >> 3, cp = chunk & 7;
    *(bf16x8*)&T[row][cp * 8] =
        *(const bf16x8*)&inp[(size_t)(s0 + row) * 1024 + d0 + cp * 8];
  }
  __syncthreads();
#pragma unroll
  for (int p = 0; p < 2; ++p) {
    int chunk = p * 256 + tx;
    int drow = chunk >> 3, cp = chunk & 7;
    bf16x8 v;
#pragma unroll
    for (int e = 0; e < 8; ++e) v[e] = (short)T[cp * 8 + e][drow];
    *(bf16x8*)&outp[(size_t)(d0 + drow) * 2048 + s0 + cp * 8] = v;
  }
}

// ---------------- gq = ge @ Wgq + bgq ----------------
__global__ void gq_init(const float* __restrict__ bgq, float* __restrict__ gq) {
  int t = blockIdx.x * 256 + threadIdx.x;   // 2048
  gq[t] = bgq[t & 1023];
}
// grid (32, 2): kb 32-row slice, b. 256 threads x 4 cols (float4).
__global__ void gq_partial(const float* __restrict__ ge, const float* __restrict__ Wgq,
                           float* __restrict__ gq) {
  int kb = blockIdx.x, b = blockIdx.y;
  int col0 = threadIdx.x * 4;
  float4v s = {0.f, 0.f, 0.f, 0.f};
  for (int k = kb * 32; k < kb * 32 + 32; ++k) {
    float g = ge[b * 1024 + k];
    float4v w = *(const float4v*)&Wgq[(size_t)k * 1024 + col0];
    s.x += g * w.x; s.y += g * w.y; s.z += g * w.z; s.w += g * w.w;
  }
  float* o = &gq[b * 1024 + col0];
  atomicAdd(&o[0], s.x); atomicAdd(&o[1], s.y);
  atomicAdd(&o[2], s.z); atomicAdd(&o[3], s.w);
}

// ---------------- flash attention, S^T orientation ----------------
// grid 512 x 256. bh = bx&31 (XCD-L2 locality), qb = bx>>5.
__global__ __launch_bounds__(256, 2) void attn_kernel(
    const u16* __restrict__ Qb, const u16* __restrict__ Kb,
    const u16* __restrict__ Vt, float* __restrict__ out,
    float* __restrict__ acc /*[0]=ent,[1]=conc*/) {
  __shared__ __align__(16) u16 Ks[128 * 64];   // [key][k], swizzled chunks
  __shared__ __align__(16) u16 Vs[64 * 128];   // [d][key], swizzled chunks
  __shared__ __align__(16) u16 Ps[4][16 * 40]; // per-wave P^T [query][key32 pad40]
  __shared__ float redE[4], redC[4];

  const int tid = threadIdx.x, lane = tid & 63, wv = tid >> 6;
  const int li = lane & 15, quad = lane >> 4;
  const int bx = blockIdx.x;
  const int bh = bx & 31, qb = bx >> 5;
  const int b = bh >> 4, h = bh & 15;
  const int wq0 = wv * 32;

  const u16* Qp = Qb + (size_t)(b * 2048 + qb * 128 + wq0) * 1024 + h * 64;
  const u16* Kp = Kb + (size_t)(b * 2048) * 1024 + h * 64;
  const u16* Vp = Vt + (size_t)b * (1024 * 2048) + (size_t)(h * 64) * 2048;

  // Q^T B-frags in registers: lane holds query=li(+16t), k=kc*32+quad*8+j
  bf16x8 qf[2][2];
#pragma unroll
  for (int t = 0; t < 2; ++t)
#pragma unroll
    for (int kc = 0; kc < 2; ++kc)
      qf[t][kc] = *(const bf16x8*)&Qp[(size_t)(t * 16 + li) * 1024 + kc * 32 + quad * 8];

  float m_st[2], l_st[2], e_st[2];
  f32x4 accO[4][2];   // O^T: rows d (mt*16+quad*4+r), cols query (li+16t)
#pragma unroll
  for (int t = 0; t < 2; ++t) { m_st[t] = -3.0e38f; l_st[t] = 0.f; e_st[t] = 0.f; }
#pragma unroll
  for (int mt = 0; mt < 4; ++mt)
#pragma unroll
    for (int t = 0; t < 2; ++t) accO[mt][t] = (f32x4){0.f, 0.f, 0.f, 0.f};

  for (int kt = 0; kt < 16; ++kt) {
    __syncthreads();
    const u16* Kpt = Kp + (size_t)(kt * 128) * 1024;
#pragma unroll
    for (int jj = 0; jj < 4; ++jj) {            // K: 8 rows x 128B per issue
      int j = wv * 4 + jj;
      int row = j * 8 + (lane >> 3);
      int c16 = (lane & 7) ^ (row & 7);
      gl_lds16(Kpt + (size_t)row * 1024 + c16 * 8, &Ks[j * 512]);
    }
#pragma unroll
    for (int jj = 0; jj < 4; ++jj) {            // V: 4 d-rows x 256B per issue
      int j = wv * 4 + jj;
      int row = j * 4 + (lane >> 4);
      int c16 = (lane & 15) ^ (row & 7);
      gl_lds16(Vp + (size_t)row * 2048 + kt * 128 + c16 * 8, &Vs[j * 512]);
    }
    __syncthreads();

    // S^T = K * Q^T : rows=keys (C-layout quad*4+r), cols=queries (li)
    f32x4 S[8][2];
#pragma unroll
    for (int u = 0; u < 8; ++u) {
      int row = u * 16 + li;
      bf16x8 a0 = *(const bf16x8*)&Ks[row * 64 + ((quad) ^ (li & 7)) * 8];
      bf16x8 a1 = *(const bf16x8*)&Ks[row * 64 + ((4 + quad) ^ (li & 7)) * 8];
#pragma unroll
      for (int t = 0; t < 2; ++t) {
        f32x4 c = {0.f, 0.f, 0.f, 0.f};
        c = __builtin_amdgcn_mfma_f32_16x16x32_bf16(a0, qf[t][0], c, 0, 0, 0);
        c = __builtin_amdgcn_mfma_f32_16x16x32_bf16(a1, qf[t][1], c, 0, 0, 0);
        S[u][t] = c;
      }
    }

    // online softmax: per-lane partials; only running max is cross-lane
    float alpha_[2];
#pragma unroll
    for (int t = 0; t < 2; ++t) {
      float cm = S[0][t][0];
#pragma unroll
      for (int u = 0; u < 8; ++u)
#pragma unroll
        for (int r = 0; r < 4; ++r) cm = fmaxf(cm, S[u][t][r]);
      cm = fmaxf(cm, __shfl_xor(cm, 16, 64));
      cm = fmaxf(cm, __shfl_xor(cm, 32, 64));
      float mo = m_st[t], mn = fmaxf(mo, cm);
      m_st[t] = mn;
      float al = __expf(mo - mn);
      alpha_[t] = al;
      float ps = 0.f, es = 0.f;
#pragma unroll
      for (int u = 0; u < 8; ++u)
#pragma unroll
        for (int r = 0; r < 4; ++r) {
          float s = S[u][t][r];
          float p = __expf(s - mn);
          ps += p;
          es = __builtin_fmaf(p, s, es);
          S[u][t][r] = p;
        }
      l_st[t] = l_st[t] * al + ps;   // per-lane partial (final reduce in epilogue)
      e_st[t] = e_st[t] * al + es;
    }
#pragma unroll
    for (int mt = 0; mt < 4; ++mt)
#pragma unroll
      for (int t = 0; t < 2; ++t) {
        accO[mt][t][0] *= alpha_[t]; accO[mt][t][1] *= alpha_[t];
        accO[mt][t][2] *= alpha_[t]; accO[mt][t][3] *= alpha_[t];
      }

    // PV: O^T += V^T * P^T, 32-key chunks; P^T via packed b64 LDS round-trip
    u16* Pw = &Ps[wv][0];
#pragma unroll
    for (int c = 0; c < 4; ++c) {
      bf16x8 av[4];
#pragma unroll
      for (int mt = 0; mt < 4; ++mt) {
        int row = mt * 16 + li;
        av[mt] = *(const bf16x8*)&Vs[row * 128 + ((c * 4 + quad) ^ (li & 7)) * 8];
      }
#pragma unroll
      for (int t = 0; t < 2; ++t) {
        uint2 w0, w1;
        w0.x = pk2(S[2 * c][t][1], S[2 * c][t][0]);
        w0.y = pk2(S[2 * c][t][3], S[2 * c][t][2]);
        w1.x = pk2(S[2 * c + 1][t][1], S[2 * c + 1][t][0]);
        w1.y = pk2(S[2 * c + 1][t][3], S[2 * c + 1][t][2]);
        *(uint2*)&Pw[li * 40 + quad * 4] = w0;        // keys 0..15 of chunk
        *(uint2*)&Pw[li * 40 + 16 + quad * 4] = w1;   // keys 16..31
        bf16x8 bp = *(const bf16x8*)&Pw[li * 40 + quad * 8];  // in-wave RAW, DS in-order
#pragma unroll
        for (int mt = 0; mt < 4; ++mt)
          accO[mt][t] = __builtin_amdgcn_mfma_f32_16x16x32_bf16(av[mt], bp, accO[mt][t], 0, 0, 0);
      }
    }
  }

  // epilogue
  float* outp = out + (size_t)(b * 2048 + qb * 128 + wq0) * 1024 + h * 64;
  float entw = 0.f, concw = 0.f;
#pragma unroll
  for (int t = 0; t < 2; ++t) {
    float lsum = l_st[t];
    lsum += __shfl_xor(lsum, 16, 64); lsum += __shfl_xor(lsum, 32, 64);
    float esum = e_st[t];
    esum += __shfl_xor(esum, 16, 64); esum += __shfl_xor(esum, 32, 64);
    float inv = 1.0f / lsum;
    entw += m_st[t] + __logf(lsum) - esum * inv;
    concw += inv;
#pragma unroll
    for (int mt = 0; mt < 4; ++mt) {
      f32x4 o = accO[mt][t];
      o[0] *= inv; o[1] *= inv; o[2] *= inv; o[3] *= inv;
      *(float4v*)&outp[(size_t)(t * 16 + li) * 1024 + mt * 16 + quad * 4] = *(float4v*)&o;
    }
  }
#pragma unroll
  for (int off = 1; off < 64; off <<= 1) {
    entw += __shfl_xor(entw, off, 64);
    concw += __shfl_xor(concw, off, 64);
  }
  if (lane == 0) { redE[wv] = entw * 0.25f; redC[wv] = concw * 0.25f; } // /4 quad dup
  __syncthreads();
  if (tid == 0) {
    atomicAdd(&acc[0], redE[0] + redE[1] + redE[2] + redE[3]);
    atomicAdd(&acc[1], redC[0] + redC[1] + redC[2] + redC[3]);
  }
}

// ---------------- influence: sum |gq . gk| over (b,h,s) ----------------
__global__ void gov_kernel(const u16* __restrict__ GKb, const float* __restrict__ gq,
                           float* __restrict__ acc_inf) {
  __shared__ float redI[4];
  int lane = threadIdx.x & 63, wv = threadIdx.x >> 6;
  int wid = blockIdx.x * 4 + wv;
  int b = wid >> 11, s = wid & 2047;
  const u16* gk = GKb + (size_t)(b * 2048 + s) * 1024 + lane * 16;
  const float* gqp = gq + b * 1024 + lane * 16;
  bf16x8 g0 = *(const bf16x8*)gk, g1 = *(const bf16x8*)(gk + 8);
  float4v q0 = *(const float4v*)&gqp[0], q1 = *(const float4v*)&gqp[4];
  float4v q2 = *(const float4v*)&gqp[8], q3 = *(const float4v*)&gqp[12];
  float sum = 0.f;
  sum += bf2f((u16)g0[0]) * q0.x + bf2f((u16)g0[1]) * q0.y +
         bf2f((u16)g0[2]) * q0.z + bf2f((u16)g0[3]) * q0.w;
  sum += bf2f((u16)g0[4]) * q1.x + bf2f((u16)g0[5]) * q1.y +
         bf2f((u16)g0[6]) * q1.z + bf2f((u16)g0[7]) * q1.w;
  sum += bf2f((u16)g1[0]) * q2.x + bf2f((u16)g1[1]) * q2.y +
         bf2f((u16)g1[2]) * q2.z + bf2f((u16)g1[3]) * q2.w;
  sum += bf2f((u16)g1[4]) * q3.x + bf2f((u16)g1[5]) * q3.y +
         bf2f((u16)g1[6]) * q3.z + bf2f((u16)g1[7]) * q3.w;
  sum += __shfl_xor(sum, 1, 64);
  sum += __shfl_xor(sum, 2, 64);
  float v = ((lane & 3) == 0) ? fabsf(sum) : 0.f;
  v += __shfl_xor(v, 4, 64);
  v += __shfl_xor(v, 8, 64);
  v += __shfl_xor(v, 16, 64);
  v += __shfl_xor(v, 32, 64);
  if (lane == 0) redI[wv] = v;
  __syncthreads();
  if (threadIdx.x == 0)
    atomicAdd(acc_inf, redI[0] + redI[1] + redI[2] + redI[3]);
}

__global__ void finalize(const float* __restrict__ acc, float* __restrict__ out) {
  if (threadIdx.x == 0) {
    out[0] = acc[0] * (1.f / 65536.f);  // entropy
    out[1] = acc[2] * (1.f / 65536.f);  // influence
    out[2] = acc[1] * (1.f / 65536.f);  // concentration
  }
}

extern "C" void kernel_launch(void* const* d_in, const int* in_sizes, int n_in,
                              void* d_out, int out_size, void* d_ws, size_t ws_size,
                              hipStream_t stream) {
  (void)in_sizes; (void)n_in; (void)out_size; (void)ws_size;
  const float* hs  = (const float*)d_in[0];
  const float* ge  = (const float*)d_in[1];
  const float* Wq  = (const float*)d_in[2];
  const float* bq  = (const float*)d_in[3];
  const float* Wk  = (const float*)d_in[4];
  const float* bk  = (const float*)d_in[5];
  const float* Wv  = (const float*)d_in[6];
  const float* bv  = (const float*)d_in[7];
  const float* Wgq = (const float*)d_in[8];
  const float* bgq = (const float*)d_in[9];
  const float* Wgk = (const float*)d_in[10];
  const float* bgk = (const float*)d_in[11];

  char* ws = (char*)d_ws;
  u16* hsB = (u16*)(ws);
  u16* WB  = (u16*)(ws + (size_t)(8 << 20));
  u16* Qb  = (u16*)(ws + (size_t)(16 << 20));
  u16* Kb  = (u16*)(ws + (size_t)(24 << 20));
  u16* Vb  = (u16*)(ws + (size_t)(32 << 20));
  u16* GKb = (u16*)(ws + (size_t)(40 << 20));
  u16* Vt  = (u16*)(ws + (size_t)(48 << 20));
  float* gq  = (float*)(ws + (size_t)(56 << 20));
  float* acc = (float*)(ws + (size_t)(56 << 20) + 16384);
  float* out = (float*)d_out;

  hipMemsetAsync(acc, 0, 3 * sizeof(float), stream);
  conv_hs<<<2048, 256, 0, stream>>>(hs, hsB);
  conv_w<<<dim3(256, 4), 256, 0, stream>>>(Wq, Wk, Wv, Wgk, WB);
  gq_init<<<8, 256, 0, stream>>>(bgq, gq);
  gemm_qkvg<<<1024, 256, 0, stream>>>(hsB, WB, bq, bk, bv, bgk, Qb, Kb, Vb, GKb);
  transpose_v<<<dim3(32, 16, 2), 256, 0, stream>>>(Vb, Vt);
  gq_partial<<<dim3(32, 2), 256, 0, stream>>>(ge, Wgq, gq);
  attn_kernel<<<512, 256, 0, stream>>>(Qb, Kb, Vt, out, acc);
  gov_kernel<<<1024, 256, 0, stream>>>(GKb, gq, acc + 2);
  finalize<<<1, 64, 0, stream>>>(acc, out + 4194304);
}